// Round 1
// baseline (479.259 us; speedup 1.0000x reference)
//
#include <hip/hip_runtime.h>
#include <math.h>

#define N_NODES 50000
#define N_EDGES 400000
#define NB_SCAN 196   // ceil(50000/256)

__device__ __forceinline__ float lrelu(float x){ return x > 0.f ? x : 0.2f*x; }

// ---------------- CSR build ----------------
__global__ void hist_k(const int* __restrict__ dst, int* __restrict__ counts){
    int e = blockIdx.x*256 + threadIdx.x;
    if (e < N_EDGES) atomicAdd(&counts[dst[e]], 1);
}

__global__ void breduce_k(const int* __restrict__ counts, int* __restrict__ bsum){
    __shared__ int s[256];
    int i = blockIdx.x*256 + threadIdx.x;
    int v = (i < N_NODES) ? counts[i] : 0;
    s[threadIdx.x] = v; __syncthreads();
    for (int d = 128; d > 0; d >>= 1){
        if (threadIdx.x < d) s[threadIdx.x] += s[threadIdx.x + d];
        __syncthreads();
    }
    if (threadIdx.x == 0) bsum[blockIdx.x] = s[0];
}

__global__ void bscan_k(const int* __restrict__ bsum, int* __restrict__ bscan){
    __shared__ int s[256];
    int t = threadIdx.x;
    int v = (t < NB_SCAN) ? bsum[t] : 0;
    s[t] = v; __syncthreads();
    for (int d = 1; d < 256; d <<= 1){
        int x = (t >= d) ? s[t-d] : 0;
        __syncthreads();
        s[t] += x;
        __syncthreads();
    }
    if (t < NB_SCAN) bscan[t] = s[t] - v;   // exclusive
}

__global__ void scanfinal_k(const int* __restrict__ counts, const int* __restrict__ bscan,
                            int* __restrict__ offsets, int* __restrict__ cursor){
    __shared__ int s[256];
    int t = threadIdx.x; int i = blockIdx.x*256 + t;
    int v = (i < N_NODES) ? counts[i] : 0;
    s[t] = v; __syncthreads();
    for (int d = 1; d < 256; d <<= 1){
        int x = (t >= d) ? s[t-d] : 0;
        __syncthreads();
        s[t] += x;
        __syncthreads();
    }
    if (i < N_NODES){
        int off = s[t] - v + bscan[blockIdx.x];
        offsets[i] = off; cursor[i] = off;
    }
}

__global__ void scatter_k(const int* __restrict__ src, const int* __restrict__ dst,
                          int* __restrict__ cursor, int* __restrict__ csr_src){
    int e = blockIdx.x*256 + threadIdx.x;
    if (e < N_EDGES){
        int d = dst[e];
        int pos = atomicAdd(&cursor[d], 1);
        csr_src[pos] = src[e];
    }
}

// ---------------- fp32 tiled GEMM: C[M x ?] = A[M x K] @ B[K x BN-block] ----------------
// BM=64, BN=64, BK=32; 256 threads, 4x4 microtile.
__global__ __launch_bounds__(256) void gemm_k(const float* __restrict__ A,
                                              const float* __restrict__ B,
                                              float* __restrict__ C,
                                              int M, int K, int ldb, int ldc){
    __shared__ float As[64*36];
    __shared__ float Bs[32*68];
    int t = threadIdx.x;
    int rows0 = blockIdx.y * 64;
    int cols0 = blockIdx.x * 64;
    int tx = t & 15, ty = t >> 4;
    float acc[4][4] = {};

    for (int k0 = 0; k0 < K; k0 += 32){
        // load A tile (64x32): thread -> row t>>2, k-chunk (t&3)*8
        int ar = rows0 + (t >> 2);
        int kc = (t & 3) * 8;
        float4 a0 = make_float4(0,0,0,0), a1 = make_float4(0,0,0,0);
        if (ar < M){
            const float* ap = A + (size_t)ar * K + k0 + kc;
            a0 = *(const float4*)ap;
            a1 = *(const float4*)(ap + 4);
        }
        *(float4*)&As[(t>>2)*36 + kc]     = a0;
        *(float4*)&As[(t>>2)*36 + kc + 4] = a1;
        // load B tile (32x64): thread -> row t>>3, col-chunk (t&7)*8
        const float* bp = B + (size_t)(k0 + (t>>3)) * ldb + cols0 + (t&7)*8;
        float4 b0 = *(const float4*)bp;
        float4 b1 = *(const float4*)(bp + 4);
        *(float4*)&Bs[(t>>3)*68 + (t&7)*8]     = b0;
        *(float4*)&Bs[(t>>3)*68 + (t&7)*8 + 4] = b1;
        __syncthreads();

        #pragma unroll
        for (int kk = 0; kk < 32; kk += 4){
            float4 a[4], b[4];
            #pragma unroll
            for (int i = 0; i < 4; i++) a[i] = *(const float4*)&As[(ty*4+i)*36 + kk];
            #pragma unroll
            for (int j = 0; j < 4; j++) b[j] = *(const float4*)&Bs[(kk+j)*68 + tx*4];
            #pragma unroll
            for (int i = 0; i < 4; i++){
                float ax[4] = {a[i].x, a[i].y, a[i].z, a[i].w};
                #pragma unroll
                for (int kq = 0; kq < 4; kq++){
                    acc[i][0] = fmaf(ax[kq], b[kq].x, acc[i][0]);
                    acc[i][1] = fmaf(ax[kq], b[kq].y, acc[i][1]);
                    acc[i][2] = fmaf(ax[kq], b[kq].z, acc[i][2]);
                    acc[i][3] = fmaf(ax[kq], b[kq].w, acc[i][3]);
                }
            }
        }
        __syncthreads();
    }

    #pragma unroll
    for (int i = 0; i < 4; i++){
        int r = rows0 + ty*4 + i;
        if (r < M){
            float4 v = make_float4(acc[i][0], acc[i][1], acc[i][2], acc[i][3]);
            *(float4*)&C[(size_t)r * ldc + cols0 + tx*4] = v;
        }
    }
}

// ---------------- attention logit dots ----------------
// conv1: h1[N,256] (2 heads x 128ch); as1/ad1[n] = (head0, head1)
__global__ void att1_k(const float* __restrict__ h1, const float* __restrict__ att_src,
                       const float* __restrict__ att_dst,
                       float2* __restrict__ as1, float2* __restrict__ ad1){
    int wid = threadIdx.x >> 6, lane = threadIdx.x & 63;
    int n = blockIdx.x*4 + wid;
    if (n >= N_NODES) return;
    const float* row = h1 + (size_t)n * 256;
    float v0 = row[lane], v1 = row[lane+64], v2 = row[128+lane], v3 = row[192+lane];
    float s0 = v0*att_src[lane]     + v1*att_src[lane+64];
    float d0 = v0*att_dst[lane]     + v1*att_dst[lane+64];
    float s1 = v2*att_src[128+lane] + v3*att_src[192+lane];
    float d1 = v2*att_dst[128+lane] + v3*att_dst[192+lane];
    for (int off = 32; off; off >>= 1){
        s0 += __shfl_down(s0, off); d0 += __shfl_down(d0, off);
        s1 += __shfl_down(s1, off); d1 += __shfl_down(d1, off);
    }
    if (lane == 0){ as1[n] = make_float2(s0, s1); ad1[n] = make_float2(d0, d1); }
}

// conv_mu/conv_ls: hml[N,128] = [hm(64) | hl(64)]; as2/ad2[n] = (mu, ls)
__global__ void att2_k(const float* __restrict__ hml,
                       const float* __restrict__ as_mu, const float* __restrict__ ad_mu,
                       const float* __restrict__ as_ls, const float* __restrict__ ad_ls,
                       float2* __restrict__ as2, float2* __restrict__ ad2){
    int wid = threadIdx.x >> 6, lane = threadIdx.x & 63;
    int n = blockIdx.x*4 + wid;
    if (n >= N_NODES) return;
    float hm = hml[(size_t)n*128 + lane];
    float hl = hml[(size_t)n*128 + 64 + lane];
    float smu = hm*as_mu[lane], dmu = hm*ad_mu[lane];
    float sls = hl*as_ls[lane], dls = hl*ad_ls[lane];
    for (int off = 32; off; off >>= 1){
        smu += __shfl_down(smu, off); dmu += __shfl_down(dmu, off);
        sls += __shfl_down(sls, off); dls += __shfl_down(dls, off);
    }
    if (lane == 0){ as2[n] = make_float2(smu, sls); ad2[n] = make_float2(dmu, dls); }
}

// ---------------- per-dst online softmax stats (2 channels at once) ----------------
__global__ void stats_k(const float2* __restrict__ as, const float2* __restrict__ ad,
                        const int* __restrict__ counts, const int* __restrict__ offsets,
                        const int* __restrict__ csr_src,
                        float2* __restrict__ m_out, float2* __restrict__ den_out){
    int n = blockIdx.x*256 + threadIdx.x;
    if (n >= N_NODES) return;
    float2 adn = ad[n], asn = as[n];
    // self-loop (src = n)
    float e0 = lrelu(asn.x + adn.x), e1 = lrelu(asn.y + adn.y);
    float m0 = e0, l0 = 1.f, m1 = e1, l1 = 1.f;
    int off = offsets[n], deg = counts[n];
    for (int k = 0; k < deg; k++){
        int s = csr_src[off + k];
        float2 a = as[s];
        float f0 = lrelu(a.x + adn.x), f1 = lrelu(a.y + adn.y);
        if (f0 > m0){ l0 = l0*__expf(m0 - f0) + 1.f; m0 = f0; } else l0 += __expf(f0 - m0);
        if (f1 > m1){ l1 = l1*__expf(m1 - f1) + 1.f; m1 = f1; } else l1 += __expf(f1 - m1);
    }
    m_out[n]   = make_float2(m0, m1);
    den_out[n] = make_float2(l0, l1);
}

// ---------------- conv1 aggregation + bias + ELU ----------------
__global__ __launch_bounds__(256) void agg1_k(const float* __restrict__ h1,
        const float2* __restrict__ as, const float2* __restrict__ ad,
        const float2* __restrict__ m, const float2* __restrict__ den,
        const int* __restrict__ counts, const int* __restrict__ offsets,
        const int* __restrict__ csr_src,
        const float* __restrict__ b1, float* __restrict__ hout){
    int n = blockIdx.x; int c = threadIdx.x; int h = c >> 7;
    float2 adn = ad[n], mn = m[n], dn = den[n], asn = as[n];
    float adh  = h ? adn.y : adn.x;
    float mh   = h ? mn.y  : mn.x;
    float invd = 1.f / ((h ? dn.y : dn.x) + 1e-16f);
    float ash  = h ? asn.y : asn.x;
    float alpha = __expf(lrelu(ash + adh) - mh) * invd;
    float acc = alpha * h1[(size_t)n*256 + c];
    int off = offsets[n], deg = counts[n];
    for (int k = 0; k < deg; k++){
        int s = csr_src[off + k];
        float2 a2 = as[s];
        float e = lrelu((h ? a2.y : a2.x) + adh);
        float al = __expf(e - mh) * invd;
        acc = fmaf(al, h1[(size_t)s*256 + c], acc);
    }
    float v = acc + b1[c];
    hout[(size_t)n*256 + c] = v > 0.f ? v : __expf(v) - 1.f;
}

// ---------------- conv_mu / conv_ls aggregation + bias, writes d_out ----------------
__global__ __launch_bounds__(128) void agg2_k(const float* __restrict__ hml,
        const float2* __restrict__ as, const float2* __restrict__ ad,
        const float2* __restrict__ m, const float2* __restrict__ den,
        const int* __restrict__ counts, const int* __restrict__ offsets,
        const int* __restrict__ csr_src,
        const float* __restrict__ b_mu, const float* __restrict__ b_ls,
        float* __restrict__ out){
    int n = blockIdx.x; int c = threadIdx.x; int g = c >> 6;
    float2 adn = ad[n], mn = m[n], dn = den[n], asn = as[n];
    float adh  = g ? adn.y : adn.x;
    float mh   = g ? mn.y  : mn.x;
    float invd = 1.f / ((g ? dn.y : dn.x) + 1e-16f);
    float ash  = g ? asn.y : asn.x;
    float alpha = __expf(lrelu(ash + adh) - mh) * invd;
    float acc = alpha * hml[(size_t)n*128 + c];
    int off = offsets[n], deg = counts[n];
    for (int k = 0; k < deg; k++){
        int s = csr_src[off + k];
        float2 a2 = as[s];
        float e = lrelu((g ? a2.y : a2.x) + adh);
        float al = __expf(e - mh) * invd;
        acc = fmaf(al, hml[(size_t)s*128 + c], acc);
    }
    if (g) out[(size_t)N_NODES*64 + (size_t)n*64 + (c - 64)] = acc + b_ls[c - 64];
    else   out[(size_t)n*64 + c] = acc + b_mu[c];
}

extern "C" void kernel_launch(void* const* d_in, const int* in_sizes, int n_in,
                              void* d_out, int out_size, void* d_ws, size_t ws_size,
                              hipStream_t stream) {
    const float* x           = (const float*)d_in[0];
    const int*   ei          = (const int*)d_in[1];
    const float* W1          = (const float*)d_in[2];
    const float* att_src1    = (const float*)d_in[3];
    const float* att_dst1    = (const float*)d_in[4];
    const float* b1          = (const float*)d_in[5];
    const float* W_mu        = (const float*)d_in[6];
    const float* att_src_mu  = (const float*)d_in[7];
    const float* att_dst_mu  = (const float*)d_in[8];
    const float* b_mu        = (const float*)d_in[9];
    const float* W_ls        = (const float*)d_in[10];
    const float* att_src_ls  = (const float*)d_in[11];
    const float* att_dst_ls  = (const float*)d_in[12];
    const float* b_ls        = (const float*)d_in[13];
    float* out = (float*)d_out;

    const int* srcp = ei;
    const int* dstp = ei + N_EDGES;

    // workspace layout
    float*  h1     = (float*)d_ws;              // [N,256]
    float*  hbuf   = h1   + (size_t)N_NODES*256; // [N,256] post-ELU
    float*  hml    = hbuf + (size_t)N_NODES*256; // [N,128] = [hm|hl]
    float2* as1    = (float2*)(hml + (size_t)N_NODES*128);
    float2* ad1    = as1  + N_NODES;
    float2* m1     = ad1  + N_NODES;
    float2* den1   = m1   + N_NODES;
    float2* as2    = den1 + N_NODES;
    float2* ad2    = as2  + N_NODES;
    float2* m2     = ad2  + N_NODES;
    float2* den2   = m2   + N_NODES;
    int*    counts = (int*)(den2 + N_NODES);
    int*    offsets= counts + N_NODES;
    int*    cursor = offsets + N_NODES;
    int*    bsum   = cursor + N_NODES;          // [256]
    int*    bscan  = bsum + 256;                // [256]
    int*    csr_src= bscan + 256;               // [E]

    const int EB = (N_EDGES + 255) / 256;

    // --- CSR build (per call; ws is re-poisoned each launch) ---
    hipMemsetAsync(counts, 0, N_NODES*sizeof(int), stream);
    hist_k<<<EB, 256, 0, stream>>>(dstp, counts);
    breduce_k<<<NB_SCAN, 256, 0, stream>>>(counts, bsum);
    bscan_k<<<1, 256, 0, stream>>>(bsum, bscan);
    scanfinal_k<<<NB_SCAN, 256, 0, stream>>>(counts, bscan, offsets, cursor);
    scatter_k<<<EB, 256, 0, stream>>>(srcp, dstp, cursor, csr_src);

    // --- conv1 ---
    gemm_k<<<dim3(4, 782), 256, 0, stream>>>(x, W1, h1, N_NODES, 128, 256, 256);
    att1_k<<<(N_NODES + 3) / 4, 256, 0, stream>>>(h1, att_src1, att_dst1, as1, ad1);
    stats_k<<<NB_SCAN, 256, 0, stream>>>(as1, ad1, counts, offsets, csr_src, m1, den1);
    agg1_k<<<N_NODES, 256, 0, stream>>>(h1, as1, ad1, m1, den1, counts, offsets, csr_src, b1, hbuf);

    // --- conv_mu / conv_ls projections (into hml cols [0,64) and [64,128)) ---
    gemm_k<<<dim3(1, 782), 256, 0, stream>>>(hbuf, W_mu, hml,      N_NODES, 256, 64, 128);
    gemm_k<<<dim3(1, 782), 256, 0, stream>>>(hbuf, W_ls, hml + 64, N_NODES, 256, 64, 128);
    att2_k<<<(N_NODES + 3) / 4, 256, 0, stream>>>(hml, att_src_mu, att_dst_mu, att_src_ls, att_dst_ls, as2, ad2);
    stats_k<<<NB_SCAN, 256, 0, stream>>>(as2, ad2, counts, offsets, csr_src, m2, den2);
    agg2_k<<<N_NODES, 128, 0, stream>>>(hml, as2, ad2, m2, den2, counts, offsets, csr_src, b_mu, b_ls, out);
}

// Round 2
// 385.727 us; speedup vs baseline: 1.2425x; 1.2425x over previous
//
#include <hip/hip_runtime.h>
#include <math.h>

#define N_NODES 50000
#define N_EDGES 400000
#define NB_SCAN 196   // ceil(50000/256)

__device__ __forceinline__ float lrelu(float x){ return x > 0.f ? x : 0.2f*x; }

// ---------------- CSR build ----------------
__global__ void hist_k(const int* __restrict__ dst, int* __restrict__ counts){
    int e = blockIdx.x*256 + threadIdx.x;
    if (e < N_EDGES) atomicAdd(&counts[dst[e]], 1);
}

__global__ void breduce_k(const int* __restrict__ counts, int* __restrict__ bsum){
    __shared__ int s[256];
    int i = blockIdx.x*256 + threadIdx.x;
    int v = (i < N_NODES) ? counts[i] : 0;
    s[threadIdx.x] = v; __syncthreads();
    for (int d = 128; d > 0; d >>= 1){
        if (threadIdx.x < d) s[threadIdx.x] += s[threadIdx.x + d];
        __syncthreads();
    }
    if (threadIdx.x == 0) bsum[blockIdx.x] = s[0];
}

__global__ void bscan_k(const int* __restrict__ bsum, int* __restrict__ bscan){
    __shared__ int s[256];
    int t = threadIdx.x;
    int v = (t < NB_SCAN) ? bsum[t] : 0;
    s[t] = v; __syncthreads();
    for (int d = 1; d < 256; d <<= 1){
        int x = (t >= d) ? s[t-d] : 0;
        __syncthreads();
        s[t] += x;
        __syncthreads();
    }
    if (t < NB_SCAN) bscan[t] = s[t] - v;   // exclusive
}

__global__ void scanfinal_k(const int* __restrict__ counts, const int* __restrict__ bscan,
                            int* __restrict__ offsets, int* __restrict__ cursor){
    __shared__ int s[256];
    int t = threadIdx.x; int i = blockIdx.x*256 + t;
    int v = (i < N_NODES) ? counts[i] : 0;
    s[t] = v; __syncthreads();
    for (int d = 1; d < 256; d <<= 1){
        int x = (t >= d) ? s[t-d] : 0;
        __syncthreads();
        s[t] += x;
        __syncthreads();
    }
    if (i < N_NODES){
        int off = s[t] - v + bscan[blockIdx.x];
        offsets[i] = off; cursor[i] = off;
    }
}

__global__ void scatter_k(const int* __restrict__ src, const int* __restrict__ dst,
                          int* __restrict__ cursor, int* __restrict__ csr_src){
    int e = blockIdx.x*256 + threadIdx.x;
    if (e < N_EDGES){
        int d = dst[e];
        int pos = atomicAdd(&cursor[d], 1);
        csr_src[pos] = src[e];
    }
}

// ---------------- fp32 tiled GEMM: C[M x ?] = A[M x K] @ B[K x BN-block] ----------------
__global__ __launch_bounds__(256) void gemm_k(const float* __restrict__ A,
                                              const float* __restrict__ B,
                                              float* __restrict__ C,
                                              int M, int K, int ldb, int ldc){
    __shared__ float As[64*36];
    __shared__ float Bs[32*68];
    int t = threadIdx.x;
    int rows0 = blockIdx.y * 64;
    int cols0 = blockIdx.x * 64;
    int tx = t & 15, ty = t >> 4;
    float acc[4][4] = {};

    for (int k0 = 0; k0 < K; k0 += 32){
        int ar = rows0 + (t >> 2);
        int kc = (t & 3) * 8;
        float4 a0 = make_float4(0,0,0,0), a1 = make_float4(0,0,0,0);
        if (ar < M){
            const float* ap = A + (size_t)ar * K + k0 + kc;
            a0 = *(const float4*)ap;
            a1 = *(const float4*)(ap + 4);
        }
        *(float4*)&As[(t>>2)*36 + kc]     = a0;
        *(float4*)&As[(t>>2)*36 + kc + 4] = a1;
        const float* bp = B + (size_t)(k0 + (t>>3)) * ldb + cols0 + (t&7)*8;
        float4 b0 = *(const float4*)bp;
        float4 b1 = *(const float4*)(bp + 4);
        *(float4*)&Bs[(t>>3)*68 + (t&7)*8]     = b0;
        *(float4*)&Bs[(t>>3)*68 + (t&7)*8 + 4] = b1;
        __syncthreads();

        #pragma unroll
        for (int kk = 0; kk < 32; kk += 4){
            float4 a[4], b[4];
            #pragma unroll
            for (int i = 0; i < 4; i++) a[i] = *(const float4*)&As[(ty*4+i)*36 + kk];
            #pragma unroll
            for (int j = 0; j < 4; j++) b[j] = *(const float4*)&Bs[(kk+j)*68 + tx*4];
            #pragma unroll
            for (int i = 0; i < 4; i++){
                float ax[4] = {a[i].x, a[i].y, a[i].z, a[i].w};
                #pragma unroll
                for (int kq = 0; kq < 4; kq++){
                    acc[i][0] = fmaf(ax[kq], b[kq].x, acc[i][0]);
                    acc[i][1] = fmaf(ax[kq], b[kq].y, acc[i][1]);
                    acc[i][2] = fmaf(ax[kq], b[kq].z, acc[i][2]);
                    acc[i][3] = fmaf(ax[kq], b[kq].w, acc[i][3]);
                }
            }
        }
        __syncthreads();
    }

    #pragma unroll
    for (int i = 0; i < 4; i++){
        int r = rows0 + ty*4 + i;
        if (r < M){
            float4 v = make_float4(acc[i][0], acc[i][1], acc[i][2], acc[i][3]);
            *(float4*)&C[(size_t)r * ldc + cols0 + tx*4] = v;
        }
    }
}

// ---------------- attention logit dots ----------------
__global__ void att1_k(const float* __restrict__ h1, const float* __restrict__ att_src,
                       const float* __restrict__ att_dst,
                       float2* __restrict__ as1, float2* __restrict__ ad1){
    int wid = threadIdx.x >> 6, lane = threadIdx.x & 63;
    int n = blockIdx.x*4 + wid;
    if (n >= N_NODES) return;
    const float* row = h1 + (size_t)n * 256;
    float v0 = row[lane], v1 = row[lane+64], v2 = row[128+lane], v3 = row[192+lane];
    float s0 = v0*att_src[lane]     + v1*att_src[lane+64];
    float d0 = v0*att_dst[lane]     + v1*att_dst[lane+64];
    float s1 = v2*att_src[128+lane] + v3*att_src[192+lane];
    float d1 = v2*att_dst[128+lane] + v3*att_dst[192+lane];
    for (int off = 32; off; off >>= 1){
        s0 += __shfl_down(s0, off); d0 += __shfl_down(d0, off);
        s1 += __shfl_down(s1, off); d1 += __shfl_down(d1, off);
    }
    if (lane == 0){ as1[n] = make_float2(s0, s1); ad1[n] = make_float2(d0, d1); }
}

__global__ void att2_k(const float* __restrict__ hml,
                       const float* __restrict__ as_mu, const float* __restrict__ ad_mu,
                       const float* __restrict__ as_ls, const float* __restrict__ ad_ls,
                       float2* __restrict__ as2, float2* __restrict__ ad2){
    int wid = threadIdx.x >> 6, lane = threadIdx.x & 63;
    int n = blockIdx.x*4 + wid;
    if (n >= N_NODES) return;
    float hm = hml[(size_t)n*128 + lane];
    float hl = hml[(size_t)n*128 + 64 + lane];
    float smu = hm*as_mu[lane], dmu = hm*ad_mu[lane];
    float sls = hl*as_ls[lane], dls = hl*ad_ls[lane];
    for (int off = 32; off; off >>= 1){
        smu += __shfl_down(smu, off); dmu += __shfl_down(dmu, off);
        sls += __shfl_down(sls, off); dls += __shfl_down(dls, off);
    }
    if (lane == 0){ as2[n] = make_float2(smu, sls); ad2[n] = make_float2(dmu, dls); }
}

// ---------------- conv1 aggregation, fused online softmax, float4, unroll-4 ----------------
// one wave per node; lane owns channels [lane*4, lane*4+4); head = lane>>5
__global__ __launch_bounds__(256) void agg1_k(const float* __restrict__ h1,
        const float2* __restrict__ as, const float2* __restrict__ ad,
        const int* __restrict__ counts, const int* __restrict__ offsets,
        const int* __restrict__ csr_src,
        const float* __restrict__ b1, float* __restrict__ hout){
    int wave = threadIdx.x >> 6, lane = threadIdx.x & 63;
    int n = blockIdx.x*4 + wave;
    if (n >= N_NODES) return;
    int head = lane >> 5;
    const float4* h1v = (const float4*)h1;

    float2 adn = ad[n], asn = as[n];
    float adh = head ? adn.y : adn.x;
    float ash = head ? asn.y : asn.x;

    // self-loop seeds the online softmax
    float m = lrelu(ash + adh);
    float l = 1.f;
    float4 acc = h1v[(size_t)n*64 + lane];

    int off = offsets[n], deg = counts[n];
    int k = 0;
    for (; k + 4 <= deg; k += 4){
        int s0 = csr_src[off+k],   s1 = csr_src[off+k+1];
        int s2 = csr_src[off+k+2], s3 = csr_src[off+k+3];
        float2 a0 = as[s0], a1 = as[s1], a2 = as[s2], a3 = as[s3];
        float4 r0 = h1v[(size_t)s0*64 + lane];
        float4 r1 = h1v[(size_t)s1*64 + lane];
        float4 r2 = h1v[(size_t)s2*64 + lane];
        float4 r3 = h1v[(size_t)s3*64 + lane];
        float e; float w; float sc;
        e = lrelu((head ? a0.y : a0.x) + adh);
        if (e > m){ sc = __expf(m-e); l = l*sc + 1.f; acc.x=acc.x*sc+r0.x; acc.y=acc.y*sc+r0.y; acc.z=acc.z*sc+r0.z; acc.w=acc.w*sc+r0.w; m = e; }
        else { w = __expf(e-m); l += w; acc.x=fmaf(w,r0.x,acc.x); acc.y=fmaf(w,r0.y,acc.y); acc.z=fmaf(w,r0.z,acc.z); acc.w=fmaf(w,r0.w,acc.w); }
        e = lrelu((head ? a1.y : a1.x) + adh);
        if (e > m){ sc = __expf(m-e); l = l*sc + 1.f; acc.x=acc.x*sc+r1.x; acc.y=acc.y*sc+r1.y; acc.z=acc.z*sc+r1.z; acc.w=acc.w*sc+r1.w; m = e; }
        else { w = __expf(e-m); l += w; acc.x=fmaf(w,r1.x,acc.x); acc.y=fmaf(w,r1.y,acc.y); acc.z=fmaf(w,r1.z,acc.z); acc.w=fmaf(w,r1.w,acc.w); }
        e = lrelu((head ? a2.y : a2.x) + adh);
        if (e > m){ sc = __expf(m-e); l = l*sc + 1.f; acc.x=acc.x*sc+r2.x; acc.y=acc.y*sc+r2.y; acc.z=acc.z*sc+r2.z; acc.w=acc.w*sc+r2.w; m = e; }
        else { w = __expf(e-m); l += w; acc.x=fmaf(w,r2.x,acc.x); acc.y=fmaf(w,r2.y,acc.y); acc.z=fmaf(w,r2.z,acc.z); acc.w=fmaf(w,r2.w,acc.w); }
        e = lrelu((head ? a3.y : a3.x) + adh);
        if (e > m){ sc = __expf(m-e); l = l*sc + 1.f; acc.x=acc.x*sc+r3.x; acc.y=acc.y*sc+r3.y; acc.z=acc.z*sc+r3.z; acc.w=acc.w*sc+r3.w; m = e; }
        else { w = __expf(e-m); l += w; acc.x=fmaf(w,r3.x,acc.x); acc.y=fmaf(w,r3.y,acc.y); acc.z=fmaf(w,r3.z,acc.z); acc.w=fmaf(w,r3.w,acc.w); }
    }
    for (; k < deg; k++){
        int s = csr_src[off+k];
        float2 a = as[s];
        float4 r = h1v[(size_t)s*64 + lane];
        float e = lrelu((head ? a.y : a.x) + adh);
        if (e > m){ float sc = __expf(m-e); l = l*sc + 1.f; acc.x=acc.x*sc+r.x; acc.y=acc.y*sc+r.y; acc.z=acc.z*sc+r.z; acc.w=acc.w*sc+r.w; m = e; }
        else { float w = __expf(e-m); l += w; acc.x=fmaf(w,r.x,acc.x); acc.y=fmaf(w,r.y,acc.y); acc.z=fmaf(w,r.z,acc.z); acc.w=fmaf(w,r.w,acc.w); }
    }

    float invl = 1.f / (l + 1e-16f);
    float4 b4 = *(const float4*)&b1[lane*4];
    float4 v;
    v.x = acc.x*invl + b4.x; v.y = acc.y*invl + b4.y;
    v.z = acc.z*invl + b4.z; v.w = acc.w*invl + b4.w;
    v.x = v.x > 0.f ? v.x : __expf(v.x) - 1.f;
    v.y = v.y > 0.f ? v.y : __expf(v.y) - 1.f;
    v.z = v.z > 0.f ? v.z : __expf(v.z) - 1.f;
    v.w = v.w > 0.f ? v.w : __expf(v.w) - 1.f;
    ((float4*)hout)[(size_t)n*64 + lane] = v;
}

// ---------------- conv_mu / conv_ls aggregation, fused online softmax ----------------
// 32 threads per node (float4 over 128 ch); block 256 = 8 nodes; g = lane>>4
__global__ __launch_bounds__(256) void agg2_k(const float* __restrict__ hml,
        const float2* __restrict__ as, const float2* __restrict__ ad,
        const int* __restrict__ counts, const int* __restrict__ offsets,
        const int* __restrict__ csr_src,
        const float* __restrict__ b_mu, const float* __restrict__ b_ls,
        float* __restrict__ out){
    int grp = threadIdx.x >> 5, lane = threadIdx.x & 31;
    int n = blockIdx.x*8 + grp;
    if (n >= N_NODES) return;
    int g = lane >> 4;   // 0 = mu, 1 = ls
    const float4* hv = (const float4*)hml;

    float2 adn = ad[n], asn = as[n];
    float adh = g ? adn.y : adn.x;
    float ash = g ? asn.y : asn.x;

    float m = lrelu(ash + adh);
    float l = 1.f;
    float4 acc = hv[(size_t)n*32 + lane];

    int off = offsets[n], deg = counts[n];
    int k = 0;
    for (; k + 4 <= deg; k += 4){
        int s0 = csr_src[off+k],   s1 = csr_src[off+k+1];
        int s2 = csr_src[off+k+2], s3 = csr_src[off+k+3];
        float2 a0 = as[s0], a1 = as[s1], a2 = as[s2], a3 = as[s3];
        float4 r0 = hv[(size_t)s0*32 + lane];
        float4 r1 = hv[(size_t)s1*32 + lane];
        float4 r2 = hv[(size_t)s2*32 + lane];
        float4 r3 = hv[(size_t)s3*32 + lane];
        float e, w, sc;
        e = lrelu((g ? a0.y : a0.x) + adh);
        if (e > m){ sc = __expf(m-e); l = l*sc + 1.f; acc.x=acc.x*sc+r0.x; acc.y=acc.y*sc+r0.y; acc.z=acc.z*sc+r0.z; acc.w=acc.w*sc+r0.w; m = e; }
        else { w = __expf(e-m); l += w; acc.x=fmaf(w,r0.x,acc.x); acc.y=fmaf(w,r0.y,acc.y); acc.z=fmaf(w,r0.z,acc.z); acc.w=fmaf(w,r0.w,acc.w); }
        e = lrelu((g ? a1.y : a1.x) + adh);
        if (e > m){ sc = __expf(m-e); l = l*sc + 1.f; acc.x=acc.x*sc+r1.x; acc.y=acc.y*sc+r1.y; acc.z=acc.z*sc+r1.z; acc.w=acc.w*sc+r1.w; m = e; }
        else { w = __expf(e-m); l += w; acc.x=fmaf(w,r1.x,acc.x); acc.y=fmaf(w,r1.y,acc.y); acc.z=fmaf(w,r1.z,acc.z); acc.w=fmaf(w,r1.w,acc.w); }
        e = lrelu((g ? a2.y : a2.x) + adh);
        if (e > m){ sc = __expf(m-e); l = l*sc + 1.f; acc.x=acc.x*sc+r2.x; acc.y=acc.y*sc+r2.y; acc.z=acc.z*sc+r2.z; acc.w=acc.w*sc+r2.w; m = e; }
        else { w = __expf(e-m); l += w; acc.x=fmaf(w,r2.x,acc.x); acc.y=fmaf(w,r2.y,acc.y); acc.z=fmaf(w,r2.z,acc.z); acc.w=fmaf(w,r2.w,acc.w); }
        e = lrelu((g ? a3.y : a3.x) + adh);
        if (e > m){ sc = __expf(m-e); l = l*sc + 1.f; acc.x=acc.x*sc+r3.x; acc.y=acc.y*sc+r3.y; acc.z=acc.z*sc+r3.z; acc.w=acc.w*sc+r3.w; m = e; }
        else { w = __expf(e-m); l += w; acc.x=fmaf(w,r3.x,acc.x); acc.y=fmaf(w,r3.y,acc.y); acc.z=fmaf(w,r3.z,acc.z); acc.w=fmaf(w,r3.w,acc.w); }
    }
    for (; k < deg; k++){
        int s = csr_src[off+k];
        float2 a = as[s];
        float4 r = hv[(size_t)s*32 + lane];
        float e = lrelu((g ? a.y : a.x) + adh);
        if (e > m){ float sc = __expf(m-e); l = l*sc + 1.f; acc.x=acc.x*sc+r.x; acc.y=acc.y*sc+r.y; acc.z=acc.z*sc+r.z; acc.w=acc.w*sc+r.w; m = e; }
        else { float w = __expf(e-m); l += w; acc.x=fmaf(w,r.x,acc.x); acc.y=fmaf(w,r.y,acc.y); acc.z=fmaf(w,r.z,acc.z); acc.w=fmaf(w,r.w,acc.w); }
    }

    float invl = 1.f / (l + 1e-16f);
    int c = (lane & 15) * 4;  // channel within the 64 of this output
    const float* bb = g ? b_ls : b_mu;
    float4 b4 = *(const float4*)&bb[c];
    float4 v;
    v.x = acc.x*invl + b4.x; v.y = acc.y*invl + b4.y;
    v.z = acc.z*invl + b4.z; v.w = acc.w*invl + b4.w;
    float* base = g ? (out + (size_t)N_NODES*64) : out;
    *(float4*)&base[(size_t)n*64 + c] = v;
}

extern "C" void kernel_launch(void* const* d_in, const int* in_sizes, int n_in,
                              void* d_out, int out_size, void* d_ws, size_t ws_size,
                              hipStream_t stream) {
    const float* x           = (const float*)d_in[0];
    const int*   ei          = (const int*)d_in[1];
    const float* W1          = (const float*)d_in[2];
    const float* att_src1    = (const float*)d_in[3];
    const float* att_dst1    = (const float*)d_in[4];
    const float* b1          = (const float*)d_in[5];
    const float* W_mu        = (const float*)d_in[6];
    const float* att_src_mu  = (const float*)d_in[7];
    const float* att_dst_mu  = (const float*)d_in[8];
    const float* b_mu        = (const float*)d_in[9];
    const float* W_ls        = (const float*)d_in[10];
    const float* att_src_ls  = (const float*)d_in[11];
    const float* att_dst_ls  = (const float*)d_in[12];
    const float* b_ls        = (const float*)d_in[13];
    float* out = (float*)d_out;

    const int* srcp = ei;
    const int* dstp = ei + N_EDGES;

    float*  h1     = (float*)d_ws;               // [N,256]
    float*  hbuf   = h1   + (size_t)N_NODES*256; // [N,256] post-ELU
    float*  hml    = hbuf + (size_t)N_NODES*256; // [N,128] = [hm|hl]
    float2* as1    = (float2*)(hml + (size_t)N_NODES*128);
    float2* ad1    = as1  + N_NODES;
    float2* as2    = ad1  + N_NODES;
    float2* ad2    = as2  + N_NODES;
    int*    counts = (int*)(ad2 + N_NODES);
    int*    offsets= counts + N_NODES;
    int*    cursor = offsets + N_NODES;
    int*    bsum   = cursor + N_NODES;           // [256]
    int*    bscan  = bsum + 256;                 // [256]
    int*    csr_src= bscan + 256;                // [E]

    const int EB = (N_EDGES + 255) / 256;

    hipMemsetAsync(counts, 0, N_NODES*sizeof(int), stream);
    hist_k<<<EB, 256, 0, stream>>>(dstp, counts);
    breduce_k<<<NB_SCAN, 256, 0, stream>>>(counts, bsum);
    bscan_k<<<1, 256, 0, stream>>>(bsum, bscan);
    scanfinal_k<<<NB_SCAN, 256, 0, stream>>>(counts, bscan, offsets, cursor);
    scatter_k<<<EB, 256, 0, stream>>>(srcp, dstp, cursor, csr_src);

    // --- conv1 ---
    gemm_k<<<dim3(4, 782), 256, 0, stream>>>(x, W1, h1, N_NODES, 128, 256, 256);
    att1_k<<<(N_NODES + 3) / 4, 256, 0, stream>>>(h1, att_src1, att_dst1, as1, ad1);
    agg1_k<<<(N_NODES + 3) / 4, 256, 0, stream>>>(h1, as1, ad1, counts, offsets, csr_src, b1, hbuf);

    // --- conv_mu / conv_ls ---
    gemm_k<<<dim3(1, 782), 256, 0, stream>>>(hbuf, W_mu, hml,      N_NODES, 256, 64, 128);
    gemm_k<<<dim3(1, 782), 256, 0, stream>>>(hbuf, W_ls, hml + 64, N_NODES, 256, 64, 128);
    att2_k<<<(N_NODES + 3) / 4, 256, 0, stream>>>(hml, att_src_mu, att_dst_mu, att_src_ls, att_dst_ls, as2, ad2);
    agg2_k<<<(N_NODES + 7) / 8, 256, 0, stream>>>(hml, as2, ad2, counts, offsets, csr_src, b_mu, b_ls, out);
}

// Round 3
// 264.686 us; speedup vs baseline: 1.8107x; 1.4573x over previous
//
#include <hip/hip_runtime.h>
#include <math.h>

#define N_NODES 50000
#define N_EDGES 400000
#define NB_SCAN 196   // ceil(50000/256)

typedef __attribute__((ext_vector_type(8))) short bf16x8;
typedef __attribute__((ext_vector_type(4))) float f32x4;

__device__ __forceinline__ float lrelu(float x){ return x > 0.f ? x : 0.2f*x; }
__device__ __forceinline__ float bf2f(unsigned short u){ return __uint_as_float(((unsigned int)u)<<16); }
__device__ __forceinline__ unsigned short f2bf(float f){
    unsigned int b = __float_as_uint(f);
    return (unsigned short)((b + 0x7FFFu + ((b>>16)&1u)) >> 16);   // RNE
}
__device__ __forceinline__ float4 bf4(ushort4 u){
    return make_float4(bf2f(u.x), bf2f(u.y), bf2f(u.z), bf2f(u.w));
}

// ---------------- CSR build ----------------
__global__ void hist_k(const int* __restrict__ dst, int* __restrict__ counts){
    int e = blockIdx.x*256 + threadIdx.x;
    if (e < N_EDGES) atomicAdd(&counts[dst[e]], 1);
}

__global__ void breduce_k(const int* __restrict__ counts, int* __restrict__ bsum){
    __shared__ int s[256];
    int i = blockIdx.x*256 + threadIdx.x;
    int v = (i < N_NODES) ? counts[i] : 0;
    s[threadIdx.x] = v; __syncthreads();
    for (int d = 128; d > 0; d >>= 1){
        if (threadIdx.x < d) s[threadIdx.x] += s[threadIdx.x + d];
        __syncthreads();
    }
    if (threadIdx.x == 0) bsum[blockIdx.x] = s[0];
}

__global__ void bscan_k(const int* __restrict__ bsum, int* __restrict__ bscan){
    __shared__ int s[256];
    int t = threadIdx.x;
    int v = (t < NB_SCAN) ? bsum[t] : 0;
    s[t] = v; __syncthreads();
    for (int d = 1; d < 256; d <<= 1){
        int x = (t >= d) ? s[t-d] : 0;
        __syncthreads();
        s[t] += x;
        __syncthreads();
    }
    if (t < NB_SCAN) bscan[t] = s[t] - v;   // exclusive
}

__global__ void scanfinal_k(const int* __restrict__ counts, const int* __restrict__ bscan,
                            int* __restrict__ offsets, int* __restrict__ cursor){
    __shared__ int s[256];
    int t = threadIdx.x; int i = blockIdx.x*256 + t;
    int v = (i < N_NODES) ? counts[i] : 0;
    s[t] = v; __syncthreads();
    for (int d = 1; d < 256; d <<= 1){
        int x = (t >= d) ? s[t-d] : 0;
        __syncthreads();
        s[t] += x;
        __syncthreads();
    }
    if (i < N_NODES){
        int off = s[t] - v + bscan[blockIdx.x];
        offsets[i] = off; cursor[i] = off;
    }
}

__global__ void scatter_k(const int* __restrict__ src, const int* __restrict__ dst,
                          int* __restrict__ cursor, int* __restrict__ csr_src){
    int e = blockIdx.x*256 + threadIdx.x;
    if (e < N_EDGES){
        int d = dst[e];
        int pos = atomicAdd(&cursor[d], 1);
        csr_src[pos] = src[e];
    }
}

// ---------------- casts ----------------
__global__ void cast_x_k(const float* __restrict__ x, unsigned short* __restrict__ xb){
    int i = blockIdx.x*256 + threadIdx.x;      // group of 4 elems
    if (i < (N_NODES*128)/4){
        float4 v = ((const float4*)x)[i];
        ushort4 o = make_ushort4(f2bf(v.x), f2bf(v.y), f2bf(v.z), f2bf(v.w));
        ((ushort4*)xb)[i] = o;
    }
}

// W1T[n][k] = W1[k][n]  (256x128);  WmlT[n][k] = {W_mu|W_ls}[k][n]  (128x256)
__global__ void cast_w_k(const float* __restrict__ W1,
                         const float* __restrict__ Wmu, const float* __restrict__ Wls,
                         unsigned short* __restrict__ W1T, unsigned short* __restrict__ WmlT){
    int i = blockIdx.x*256 + threadIdx.x;
    if (i < 32768){
        int n = i >> 7, k = i & 127;
        W1T[i] = f2bf(W1[k*256 + n]);
    }
    if (i < 32768){
        int n = i >> 8, k = i & 255;
        float v = (n < 64) ? Wmu[k*64 + n] : Wls[k*64 + (n-64)];
        WmlT[i] = f2bf(v);
    }
}

// ---------------- bf16 MFMA GEMM: C[M x N] = A[M x K] @ BT[N x K]^T ----------------
// 128x128 tile, BK=32, 256 threads (4 waves 2x2), 4x4 frags of 16x16x32.
// Rows clamped to M-1 for OOB (stores guarded). N, K multiples of 128/32.
__global__ __launch_bounds__(256) void mfma_gemm_k(const unsigned short* __restrict__ A,
                                                   const unsigned short* __restrict__ BT,
                                                   unsigned short* __restrict__ C,
                                                   int M, int K, int ldc){
    __shared__ unsigned short As[128*40];   // +8 elem pad: 2-way bank conflicts only
    __shared__ unsigned short Bs[128*40];
    int t = threadIdx.x;
    int lane = t & 63, wid = t >> 6;
    int wy = wid >> 1, wx = wid & 1;
    int quad = lane >> 4, l15 = lane & 15;
    int row0 = blockIdx.y * 128;
    int col0 = blockIdx.x * 128;

    f32x4 acc[4][4];
    #pragma unroll
    for (int i = 0; i < 4; i++)
        #pragma unroll
        for (int j = 0; j < 4; j++)
            acc[i][j] = (f32x4){0.f, 0.f, 0.f, 0.f};

    int r = t >> 2;              // 0..63
    int cofs = (t & 3) * 8;      // elem offset in k-slice

    for (int k0 = 0; k0 < K; k0 += 32){
        int gr0 = min(row0 + r,      M-1);
        int gr1 = min(row0 + r + 64, M-1);
        float4 av0 = *(const float4*)(A  + (size_t)gr0*K + k0 + cofs);
        float4 av1 = *(const float4*)(A  + (size_t)gr1*K + k0 + cofs);
        float4 bv0 = *(const float4*)(BT + (size_t)(col0 + r)*K      + k0 + cofs);
        float4 bv1 = *(const float4*)(BT + (size_t)(col0 + r + 64)*K + k0 + cofs);
        __syncthreads();
        *(float4*)&As[r*40 + cofs]      = av0;
        *(float4*)&As[(r+64)*40 + cofs] = av1;
        *(float4*)&Bs[r*40 + cofs]      = bv0;
        *(float4*)&Bs[(r+64)*40 + cofs] = bv1;
        __syncthreads();

        bf16x8 af[4], bf[4];
        #pragma unroll
        for (int i = 0; i < 4; i++)
            af[i] = *(const bf16x8*)&As[(wy*64 + i*16 + l15)*40 + quad*8];
        #pragma unroll
        for (int j = 0; j < 4; j++)
            bf[j] = *(const bf16x8*)&Bs[(wx*64 + j*16 + l15)*40 + quad*8];
        #pragma unroll
        for (int i = 0; i < 4; i++)
            #pragma unroll
            for (int j = 0; j < 4; j++)
                acc[i][j] = __builtin_amdgcn_mfma_f32_16x16x32_bf16(af[i], bf[j], acc[i][j], 0, 0, 0);
    }

    // epilogue: C/D layout col=lane&15, row=quad*4+reg  [m89-verified]
    #pragma unroll
    for (int i = 0; i < 4; i++){
        #pragma unroll
        for (int reg = 0; reg < 4; reg++){
            int rr = row0 + wy*64 + i*16 + quad*4 + reg;
            if (rr < M){
                #pragma unroll
                for (int j = 0; j < 4; j++){
                    int cc = col0 + wx*64 + j*16 + l15;
                    C[(size_t)rr*ldc + cc] = f2bf(acc[i][j][reg]);
                }
            }
        }
    }
}

// ---------------- attention logit dots (bf16 inputs, fp32 math) ----------------
__global__ void att1_k(const unsigned short* __restrict__ h1,
                       const float* __restrict__ att_src, const float* __restrict__ att_dst,
                       float2* __restrict__ as1, float2* __restrict__ ad1){
    int wid = threadIdx.x >> 6, lane = threadIdx.x & 63;
    int n = blockIdx.x*4 + wid;
    if (n >= N_NODES) return;
    ushort4 u = ((const ushort4*)(h1 + (size_t)n*256))[lane];
    float4 f = bf4(u);
    int head = lane >> 5;
    int cbase = head*128 + (lane & 31)*4;
    float s = f.x*att_src[cbase] + f.y*att_src[cbase+1] + f.z*att_src[cbase+2] + f.w*att_src[cbase+3];
    float d = f.x*att_dst[cbase] + f.y*att_dst[cbase+1] + f.z*att_dst[cbase+2] + f.w*att_dst[cbase+3];
    for (int off = 16; off; off >>= 1){
        s += __shfl_down(s, off, 32);
        d += __shfl_down(d, off, 32);
    }
    float s0 = __shfl(s, 0), s1 = __shfl(s, 32);
    float d0 = __shfl(d, 0), d1 = __shfl(d, 32);
    if (lane == 0){ as1[n] = make_float2(s0, s1); ad1[n] = make_float2(d0, d1); }
}

__global__ void att2_k(const unsigned short* __restrict__ hml,
                       const float* __restrict__ as_mu, const float* __restrict__ ad_mu,
                       const float* __restrict__ as_ls, const float* __restrict__ ad_ls,
                       float2* __restrict__ as2, float2* __restrict__ ad2){
    int wid = threadIdx.x >> 6, lane = threadIdx.x & 63;
    int n = blockIdx.x*4 + wid;
    if (n >= N_NODES) return;
    ushort2 u = ((const ushort2*)(hml + (size_t)n*128))[lane];
    float f0 = bf2f(u.x), f1 = bf2f(u.y);
    int g = lane >> 5;                       // 0 = mu (ch 0-63), 1 = ls (ch 64-127)
    int c = (lane & 31)*2;
    const float* ws = g ? as_ls : as_mu;
    const float* wd = g ? ad_ls : ad_mu;
    float s = f0*ws[c] + f1*ws[c+1];
    float d = f0*wd[c] + f1*wd[c+1];
    for (int off = 16; off; off >>= 1){
        s += __shfl_down(s, off, 32);
        d += __shfl_down(d, off, 32);
    }
    float s0 = __shfl(s, 0), s1 = __shfl(s, 32);
    float d0 = __shfl(d, 0), d1 = __shfl(d, 32);
    if (lane == 0){ as2[n] = make_float2(s0, s1); ad2[n] = make_float2(d0, d1); }
}

// ---------------- conv1 aggregation: bf16 gather, fused online softmax ----------------
// one wave per node; lane owns 4 channels (ushort4); head = lane>>5
__global__ __launch_bounds__(256) void agg1_k(const unsigned short* __restrict__ h1,
        const float2* __restrict__ as, const float2* __restrict__ ad,
        const int* __restrict__ counts, const int* __restrict__ offsets,
        const int* __restrict__ csr_src,
        const float* __restrict__ b1, unsigned short* __restrict__ hout){
    int wave = threadIdx.x >> 6, lane = threadIdx.x & 63;
    int n = blockIdx.x*4 + wave;
    if (n >= N_NODES) return;
    int head = lane >> 5;
    const ushort4* h1v = (const ushort4*)h1;

    float2 adn = ad[n], asn = as[n];
    float adh = head ? adn.y : adn.x;
    float ash = head ? asn.y : asn.x;

    float m = lrelu(ash + adh);
    float l = 1.f;
    float4 acc = bf4(h1v[(size_t)n*64 + lane]);

    int off = offsets[n], deg = counts[n];
    int k = 0;
    for (; k + 4 <= deg; k += 4){
        int s0 = csr_src[off+k],   s1 = csr_src[off+k+1];
        int s2 = csr_src[off+k+2], s3 = csr_src[off+k+3];
        float2 a0 = as[s0], a1 = as[s1], a2 = as[s2], a3 = as[s3];
        float4 r0 = bf4(h1v[(size_t)s0*64 + lane]);
        float4 r1 = bf4(h1v[(size_t)s1*64 + lane]);
        float4 r2 = bf4(h1v[(size_t)s2*64 + lane]);
        float4 r3 = bf4(h1v[(size_t)s3*64 + lane]);
        float e, w, sc;
        e = lrelu((head ? a0.y : a0.x) + adh);
        if (e > m){ sc = __expf(m-e); l = l*sc + 1.f; acc.x=acc.x*sc+r0.x; acc.y=acc.y*sc+r0.y; acc.z=acc.z*sc+r0.z; acc.w=acc.w*sc+r0.w; m = e; }
        else { w = __expf(e-m); l += w; acc.x=fmaf(w,r0.x,acc.x); acc.y=fmaf(w,r0.y,acc.y); acc.z=fmaf(w,r0.z,acc.z); acc.w=fmaf(w,r0.w,acc.w); }
        e = lrelu((head ? a1.y : a1.x) + adh);
        if (e > m){ sc = __expf(m-e); l = l*sc + 1.f; acc.x=acc.x*sc+r1.x; acc.y=acc.y*sc+r1.y; acc.z=acc.z*sc+r1.z; acc.w=acc.w*sc+r1.w; m = e; }
        else { w = __expf(e-m); l += w; acc.x=fmaf(w,r1.x,acc.x); acc.y=fmaf(w,r1.y,acc.y); acc.z=fmaf(w,r1.z,acc.z); acc.w=fmaf(w,r1.w,acc.w); }
        e = lrelu((head ? a2.y : a2.x) + adh);
        if (e > m){ sc = __expf(m-e); l = l*sc + 1.f; acc.x=acc.x*sc+r2.x; acc.y=acc.y*sc+r2.y; acc.z=acc.z*sc+r2.z; acc.w=acc.w*sc+r2.w; m = e; }
        else { w = __expf(e-m); l += w; acc.x=fmaf(w,r2.x,acc.x); acc.y=fmaf(w,r2.y,acc.y); acc.z=fmaf(w,r2.z,acc.z); acc.w=fmaf(w,r2.w,acc.w); }
        e = lrelu((head ? a3.y : a3.x) + adh);
        if (e > m){ sc = __expf(m-e); l = l*sc + 1.f; acc.x=acc.x*sc+r3.x; acc.y=acc.y*sc+r3.y; acc.z=acc.z*sc+r3.z; acc.w=acc.w*sc+r3.w; m = e; }
        else { w = __expf(e-m); l += w; acc.x=fmaf(w,r3.x,acc.x); acc.y=fmaf(w,r3.y,acc.y); acc.z=fmaf(w,r3.z,acc.z); acc.w=fmaf(w,r3.w,acc.w); }
    }
    for (; k < deg; k++){
        int s = csr_src[off+k];
        float2 a = as[s];
        float4 r = bf4(h1v[(size_t)s*64 + lane]);
        float e = lrelu((head ? a.y : a.x) + adh);
        if (e > m){ float sc = __expf(m-e); l = l*sc + 1.f; acc.x=acc.x*sc+r.x; acc.y=acc.y*sc+r.y; acc.z=acc.z*sc+r.z; acc.w=acc.w*sc+r.w; m = e; }
        else { float w = __expf(e-m); l += w; acc.x=fmaf(w,r.x,acc.x); acc.y=fmaf(w,r.y,acc.y); acc.z=fmaf(w,r.z,acc.z); acc.w=fmaf(w,r.w,acc.w); }
    }

    float invl = 1.f / (l + 1e-16f);
    float4 b4 = *(const float4*)&b1[lane*4];
    float4 v;
    v.x = acc.x*invl + b4.x; v.y = acc.y*invl + b4.y;
    v.z = acc.z*invl + b4.z; v.w = acc.w*invl + b4.w;
    v.x = v.x > 0.f ? v.x : __expf(v.x) - 1.f;
    v.y = v.y > 0.f ? v.y : __expf(v.y) - 1.f;
    v.z = v.z > 0.f ? v.z : __expf(v.z) - 1.f;
    v.w = v.w > 0.f ? v.w : __expf(v.w) - 1.f;
    ((ushort4*)hout)[(size_t)n*64 + lane] = make_ushort4(f2bf(v.x), f2bf(v.y), f2bf(v.z), f2bf(v.w));
}

// ---------------- conv_mu / conv_ls aggregation: bf16 gather ----------------
// 32 threads per node; lane owns 4 channels; g = lane>>4 (0=mu, 1=ls)
__global__ __launch_bounds__(256) void agg2_k(const unsigned short* __restrict__ hml,
        const float2* __restrict__ as, const float2* __restrict__ ad,
        const int* __restrict__ counts, const int* __restrict__ offsets,
        const int* __restrict__ csr_src,
        const float* __restrict__ b_mu, const float* __restrict__ b_ls,
        float* __restrict__ out){
    int grp = threadIdx.x >> 5, lane = threadIdx.x & 31;
    int n = blockIdx.x*8 + grp;
    if (n >= N_NODES) return;
    int g = lane >> 4;
    const ushort4* hv = (const ushort4*)hml;

    float2 adn = ad[n], asn = as[n];
    float adh = g ? adn.y : adn.x;
    float ash = g ? asn.y : asn.x;

    float m = lrelu(ash + adh);
    float l = 1.f;
    float4 acc = bf4(hv[(size_t)n*32 + lane]);

    int off = offsets[n], deg = counts[n];
    int k = 0;
    for (; k + 4 <= deg; k += 4){
        int s0 = csr_src[off+k],   s1 = csr_src[off+k+1];
        int s2 = csr_src[off+k+2], s3 = csr_src[off+k+3];
        float2 a0 = as[s0], a1 = as[s1], a2 = as[s2], a3 = as[s3];
        float4 r0 = bf4(hv[(size_t)s0*32 + lane]);
        float4 r1 = bf4(hv[(size_t)s1*32 + lane]);
        float4 r2 = bf4(hv[(size_t)s2*32 + lane]);
        float4 r3 = bf4(hv[(size_t)s3*32 + lane]);
        float e, w, sc;
        e = lrelu((g ? a0.y : a0.x) + adh);
        if (e > m){ sc = __expf(m-e); l = l*sc + 1.f; acc.x=acc.x*sc+r0.x; acc.y=acc.y*sc+r0.y; acc.z=acc.z*sc+r0.z; acc.w=acc.w*sc+r0.w; m = e; }
        else { w = __expf(e-m); l += w; acc.x=fmaf(w,r0.x,acc.x); acc.y=fmaf(w,r0.y,acc.y); acc.z=fmaf(w,r0.z,acc.z); acc.w=fmaf(w,r0.w,acc.w); }
        e = lrelu((g ? a1.y : a1.x) + adh);
        if (e > m){ sc = __expf(m-e); l = l*sc + 1.f; acc.x=acc.x*sc+r1.x; acc.y=acc.y*sc+r1.y; acc.z=acc.z*sc+r1.z; acc.w=acc.w*sc+r1.w; m = e; }
        else { w = __expf(e-m); l += w; acc.x=fmaf(w,r1.x,acc.x); acc.y=fmaf(w,r1.y,acc.y); acc.z=fmaf(w,r1.z,acc.z); acc.w=fmaf(w,r1.w,acc.w); }
        e = lrelu((g ? a2.y : a2.x) + adh);
        if (e > m){ sc = __expf(m-e); l = l*sc + 1.f; acc.x=acc.x*sc+r2.x; acc.y=acc.y*sc+r2.y; acc.z=acc.z*sc+r2.z; acc.w=acc.w*sc+r2.w; m = e; }
        else { w = __expf(e-m); l += w; acc.x=fmaf(w,r2.x,acc.x); acc.y=fmaf(w,r2.y,acc.y); acc.z=fmaf(w,r2.z,acc.z); acc.w=fmaf(w,r2.w,acc.w); }
        e = lrelu((g ? a3.y : a3.x) + adh);
        if (e > m){ sc = __expf(m-e); l = l*sc + 1.f; acc.x=acc.x*sc+r3.x; acc.y=acc.y*sc+r3.y; acc.z=acc.z*sc+r3.z; acc.w=acc.w*sc+r3.w; m = e; }
        else { w = __expf(e-m); l += w; acc.x=fmaf(w,r3.x,acc.x); acc.y=fmaf(w,r3.y,acc.y); acc.z=fmaf(w,r3.z,acc.z); acc.w=fmaf(w,r3.w,acc.w); }
    }
    for (; k < deg; k++){
        int s = csr_src[off+k];
        float2 a = as[s];
        float4 r = bf4(hv[(size_t)s*32 + lane]);
        float e = lrelu((g ? a.y : a.x) + adh);
        if (e > m){ float sc = __expf(m-e); l = l*sc + 1.f; acc.x=acc.x*sc+r.x; acc.y=acc.y*sc+r.y; acc.z=acc.z*sc+r.z; acc.w=acc.w*sc+r.w; m = e; }
        else { float w = __expf(e-m); l += w; acc.x=fmaf(w,r.x,acc.x); acc.y=fmaf(w,r.y,acc.y); acc.z=fmaf(w,r.z,acc.z); acc.w=fmaf(w,r.w,acc.w); }
    }

    float invl = 1.f / (l + 1e-16f);
    int c = (lane & 15) * 4;
    const float* bb = g ? b_ls : b_mu;
    float4 b4 = *(const float4*)&bb[c];
    float4 v;
    v.x = acc.x*invl + b4.x; v.y = acc.y*invl + b4.y;
    v.z = acc.z*invl + b4.z; v.w = acc.w*invl + b4.w;
    float* base = g ? (out + (size_t)N_NODES*64) : out;
    *(float4*)&base[(size_t)n*64 + c] = v;
}

extern "C" void kernel_launch(void* const* d_in, const int* in_sizes, int n_in,
                              void* d_out, int out_size, void* d_ws, size_t ws_size,
                              hipStream_t stream) {
    const float* x           = (const float*)d_in[0];
    const int*   ei          = (const int*)d_in[1];
    const float* W1          = (const float*)d_in[2];
    const float* att_src1    = (const float*)d_in[3];
    const float* att_dst1    = (const float*)d_in[4];
    const float* b1          = (const float*)d_in[5];
    const float* W_mu        = (const float*)d_in[6];
    const float* att_src_mu  = (const float*)d_in[7];
    const float* att_dst_mu  = (const float*)d_in[8];
    const float* b_mu        = (const float*)d_in[9];
    const float* W_ls        = (const float*)d_in[10];
    const float* att_src_ls  = (const float*)d_in[11];
    const float* att_dst_ls  = (const float*)d_in[12];
    const float* b_ls        = (const float*)d_in[13];
    float* out = (float*)d_out;

    const int* srcp = ei;
    const int* dstp = ei + N_EDGES;

    // workspace layout (bf16 stored as unsigned short)
    unsigned short* xb   = (unsigned short*)d_ws;            // [N,128]
    unsigned short* h1   = xb   + (size_t)N_NODES*128;       // [N,256]
    unsigned short* hbuf = h1   + (size_t)N_NODES*256;       // [N,256] post-ELU
    unsigned short* hml  = hbuf + (size_t)N_NODES*256;       // [N,128] = [hm|hl]
    unsigned short* W1T  = hml  + (size_t)N_NODES*128;       // [256,128]
    unsigned short* WmlT = W1T  + 32768;                     // [128,256]
    float2* as1    = (float2*)(WmlT + 32768);
    float2* ad1    = as1  + N_NODES;
    float2* as2    = ad1  + N_NODES;
    float2* ad2    = as2  + N_NODES;
    int*    counts = (int*)(ad2 + N_NODES);
    int*    offsets= counts + N_NODES;
    int*    cursor = offsets + N_NODES;
    int*    bsum   = cursor + N_NODES;          // [256]
    int*    bscan  = bsum + 256;                // [256]
    int*    csr_src= bscan + 256;               // [E]

    const int EB = (N_EDGES + 255) / 256;

    // --- CSR build ---
    hipMemsetAsync(counts, 0, N_NODES*sizeof(int), stream);
    hist_k<<<EB, 256, 0, stream>>>(dstp, counts);
    breduce_k<<<NB_SCAN, 256, 0, stream>>>(counts, bsum);
    bscan_k<<<1, 256, 0, stream>>>(bsum, bscan);
    scanfinal_k<<<NB_SCAN, 256, 0, stream>>>(counts, bscan, offsets, cursor);
    scatter_k<<<EB, 256, 0, stream>>>(srcp, dstp, cursor, csr_src);

    // --- casts ---
    cast_x_k<<<(N_NODES*128/4 + 255)/256, 256, 0, stream>>>(x, xb);
    cast_w_k<<<128, 256, 0, stream>>>(W1, W_mu, W_ls, W1T, WmlT);

    // --- conv1: h1[N,256] = xb @ W1T^T ---
    mfma_gemm_k<<<dim3(2, 391), 256, 0, stream>>>(xb, W1T, h1, N_NODES, 128, 256);
    att1_k<<<(N_NODES + 3) / 4, 256, 0, stream>>>(h1, att_src1, att_dst1, as1, ad1);
    agg1_k<<<(N_NODES + 3) / 4, 256, 0, stream>>>(h1, as1, ad1, counts, offsets, csr_src, b1, hbuf);

    // --- conv_mu + conv_ls fused: hml[N,128] = hbuf @ WmlT^T ---
    mfma_gemm_k<<<dim3(1, 391), 256, 0, stream>>>(hbuf, WmlT, hml, N_NODES, 256, 128);
    att2_k<<<(N_NODES + 3) / 4, 256, 0, stream>>>(hml, att_src_mu, att_dst_mu, att_src_ls, att_dst_ls, as2, ad2);
    agg2_k<<<(N_NODES + 7) / 8, 256, 0, stream>>>(hml, as2, ad2, counts, offsets, csr_src, b_mu, b_ls, out);
}